// Round 1
// baseline (826.179 us; speedup 1.0000x reference)
//
#include <hip/hip_runtime.h>

// Logical row index I (0..NLOG-1) -> padded LDS word index: one pad word per 16.
// Lane t's addresses become 17*t + const  => <=2 lanes/bank => conflict-free.
#define PADW(I) ((I) + ((I) >> 4))

constexpr int LROW = 4096;
constexpr int KW   = 64;
constexpr int HALO = 32;                      // pad_lo=31, pad_hi=32; use 32 both sides
constexpr int NLOG = LROW + 2 * HALO;         // 4160 logical words incl. halo
constexpr int XS_SIZE = PADW(NLOG - 1) + 1;   // 4419 words (~17.3 KB)

// conv over this thread's 16 consecutive elements with register window reuse:
// acc[e] = sum_j kn[j] * x[16t + e + j - 31]; window w[m]=x(I=16t+1+m), m=e+j.
__device__ __forceinline__ void conv_row(const float* __restrict__ xs,
                                         const float* __restrict__ kn,
                                         int t, float acc[16]) {
#pragma unroll
  for (int e = 0; e < 16; ++e) acc[e] = 0.0f;
  const int base = 16 * t + 1;
#pragma unroll
  for (int m = 0; m < 79; ++m) {
    float wv = xs[PADW(base + m)];
    const int jlo = (m - 15 > 0) ? (m - 15) : 0;
    const int jhi = (m < 63) ? m : 63;
#pragma unroll
    for (int j = jlo; j <= jhi; ++j) {
      acc[m - j] = fmaf(kn[j], wv, acc[m - j]);
    }
  }
}

__global__ __launch_bounds__(256) void ista_kernel(
    const float* __restrict__ y, const float* __restrict__ pulse,
    float* __restrict__ xout) {
  __shared__ float xs[XS_SIZE];
  __shared__ float pl[KW];
  __shared__ float kn[KW];

  const int t = threadIdx.x;
  const int row = blockIdx.x;

  if (t < KW) pl[t] = pulse[t];
  if (t < HALO) {                       // zero halos (stay zero forever)
    xs[PADW(t)] = 0.0f;
    xs[PADW(NLOG - HALO + t)] = 0.0f;
  }
  // stage y row into xs (coalesced float4 loads)
  const float* yrow = y + (size_t)row * LROW;
#pragma unroll
  for (int q = 0; q < 4; ++q) {
    int i4 = q * 256 + t;
    float4 v = ((const float4*)yrow)[i4];
    xs[PADW(HALO + 4 * i4 + 0)] = v.x;
    xs[PADW(HALO + 4 * i4 + 1)] = v.y;
    xs[PADW(HALO + 4 * i4 + 2)] = v.z;
    xs[PADW(HALO + 4 * i4 + 3)] = v.w;
  }
  __syncthreads();

  // L_const = sum pulse^2 (redundant per-thread, broadcast LDS reads, once)
  float Lc = 0.0f;
#pragma unroll
  for (int j = 0; j < KW; ++j) Lc += pl[j] * pl[j];
  const float theta = 0.1f / Lc;
  if (t < KW) kn[t] = pl[KW - 1 - t] / Lc;   // reversed pulse, pre-divided by L
  __syncthreads();

  // B_term = conv(y)/L  (kn already folded); kept in registers for all iters
  float bt[16];
  conv_row(xs, kn, t, bt);
  __syncthreads();

  // iteration 1: x1 = shrink(B_term)  (since x0 = 0 => conv term vanishes)
#pragma unroll
  for (int e = 0; e < 16; ++e) {
    float c = bt[e];
    float a = fabsf(c) - theta;
    xs[PADW(HALO + 16 * t + e)] = (a > 0.0f) ? copysignf(a, c) : 0.0f;
  }
  __syncthreads();

  // remaining 19 ISTA iterations entirely in LDS/registers
  for (int it = 0; it < 19; ++it) {
    float acc[16];
    conv_row(xs, kn, t, acc);
    float xn[16];
#pragma unroll
    for (int e = 0; e < 16; ++e) {
      float xcur = xs[PADW(HALO + 16 * t + e)];
      float c = bt[e] + xcur - acc[e];
      float a = fabsf(c) - theta;
      xn[e] = (a > 0.0f) ? copysignf(a, c) : 0.0f;
    }
    __syncthreads();                     // all reads of old x done
#pragma unroll
    for (int e = 0; e < 16; ++e) xs[PADW(HALO + 16 * t + e)] = xn[e];
    __syncthreads();                     // new x visible to all
  }

  // write x out, coalesced float4
  float* xr = xout + (size_t)row * LROW;
#pragma unroll
  for (int q = 0; q < 4; ++q) {
    int i4 = q * 256 + t;
    float4 v;
    v.x = xs[PADW(HALO + 4 * i4 + 0)];
    v.y = xs[PADW(HALO + 4 * i4 + 1)];
    v.z = xs[PADW(HALO + 4 * i4 + 2)];
    v.w = xs[PADW(HALO + 4 * i4 + 3)];
    ((float4*)xr)[i4] = v;
  }
}

// ---------------- MLP: features = relu(x @ W1 + b1); peak = (f @ W2 + b2)*4096
constexpr int TK = 512;      // K tile
constexpr int MROWS = 16;    // rows per block

__global__ __launch_bounds__(256) void mlp_kernel(
    const float* __restrict__ x, const float* __restrict__ W1,
    const float* __restrict__ b1, const float* __restrict__ W2,
    const float* __restrict__ b2, float* __restrict__ out1) {
  __shared__ __align__(16) float xT[TK * 20];  // stride 20 -> float4-aligned rows
  __shared__ float red[MROWS * 4];

  const int t = threadIdx.x;       // t = feature column c (H = 256)
  const int r0 = blockIdx.x * MROWS;

  float acc[MROWS];
#pragma unroll
  for (int r = 0; r < MROWS; ++r) acc[r] = 0.0f;

  for (int kt = 0; kt < LROW; kt += TK) {
    // stage x^T tile: xT[k*20 + r] = x[r0+r][kt+k]
#pragma unroll
    for (int r = 0; r < MROWS; ++r) {
#pragma unroll
      for (int q = 0; q < TK / 256; ++q) {
        int k = q * 256 + t;
        xT[k * 20 + r] = x[(size_t)(r0 + r) * LROW + kt + k];
      }
    }
    __syncthreads();
#pragma unroll 4
    for (int k = 0; k < TK; ++k) {
      float wv = W1[(size_t)(kt + k) * 256 + t];     // coalesced, L3-resident
      const float4* xp = (const float4*)&xT[k * 20]; // broadcast reads
      float4 a0 = xp[0], a1 = xp[1], a2 = xp[2], a3 = xp[3];
      acc[0]  = fmaf(a0.x, wv, acc[0]);
      acc[1]  = fmaf(a0.y, wv, acc[1]);
      acc[2]  = fmaf(a0.z, wv, acc[2]);
      acc[3]  = fmaf(a0.w, wv, acc[3]);
      acc[4]  = fmaf(a1.x, wv, acc[4]);
      acc[5]  = fmaf(a1.y, wv, acc[5]);
      acc[6]  = fmaf(a1.z, wv, acc[6]);
      acc[7]  = fmaf(a1.w, wv, acc[7]);
      acc[8]  = fmaf(a2.x, wv, acc[8]);
      acc[9]  = fmaf(a2.y, wv, acc[9]);
      acc[10] = fmaf(a2.z, wv, acc[10]);
      acc[11] = fmaf(a2.w, wv, acc[11]);
      acc[12] = fmaf(a3.x, wv, acc[12]);
      acc[13] = fmaf(a3.y, wv, acc[13]);
      acc[14] = fmaf(a3.z, wv, acc[14]);
      acc[15] = fmaf(a3.w, wv, acc[15]);
    }
    __syncthreads();
  }

  const float b1v = b1[t];
  const float w2v = W2[t];
#pragma unroll
  for (int r = 0; r < MROWS; ++r) {
    float f = acc[r] + b1v;
    f = (f > 0.0f) ? f : 0.0f;
    float p = f * w2v;
#pragma unroll
    for (int off = 32; off > 0; off >>= 1) p += __shfl_down(p, off, 64);
    if ((t & 63) == 0) red[r * 4 + (t >> 6)] = p;
  }
  __syncthreads();
  if (t < MROWS) {
    float s = red[t * 4 + 0] + red[t * 4 + 1] + red[t * 4 + 2] + red[t * 4 + 3] + b2[0];
    out1[r0 + t] = s * (float)LROW;
  }
}

extern "C" void kernel_launch(void* const* d_in, const int* in_sizes, int n_in,
                              void* d_out, int out_size, void* d_ws, size_t ws_size,
                              hipStream_t stream) {
  const float* y     = (const float*)d_in[0];
  const float* pulse = (const float*)d_in[1];
  const float* W1    = (const float*)d_in[2];
  const float* b1    = (const float*)d_in[3];
  const float* W2    = (const float*)d_in[4];
  const float* b2    = (const float*)d_in[5];

  float* xout = (float*)d_out;                       // output 0: x (4096x4096)
  float* out1 = xout + (size_t)LROW * LROW;          // output 1: peak_pred (4096)

  ista_kernel<<<LROW, 256, 0, stream>>>(y, pulse, xout);
  mlp_kernel<<<LROW / MROWS, 256, 0, stream>>>(xout, W1, b1, W2, b2, out1);
}

// Round 2
// 594.850 us; speedup vs baseline: 1.3889x; 1.3889x over previous
//
#include <hip/hip_runtime.h>

typedef __attribute__((ext_vector_type(4))) float f32x4;
typedef __attribute__((ext_vector_type(8))) short short8;
typedef __attribute__((ext_vector_type(4))) short short4v;

// Logical row index I -> padded LDS word index: one pad word per 16.
// Lane t's addresses become 17*t + const => <=2 lanes/bank => conflict-free.
#define PADW(I) ((I) + ((I) >> 4))

constexpr int LROW = 4096;
constexpr int KW   = 64;
constexpr int HALO = 32;
constexpr int NLOG = LROW + 2 * HALO;
constexpr int XS_SIZE = PADW(NLOG - 1) + 1;   // 4419 words

__device__ __forceinline__ float shrinkf(float c, float theta) {
  float a = fabsf(c) - theta;
  return (a > 0.0f) ? copysignf(a, c) : 0.0f;
}

// conv over this thread's 16 consecutive elements with register window reuse.
__device__ __forceinline__ void conv_row(const float* __restrict__ xs,
                                         const float* __restrict__ kn,
                                         int t, float acc[16]) {
#pragma unroll
  for (int e = 0; e < 16; ++e) acc[e] = 0.0f;
  const int base = 16 * t + 1;
#pragma unroll
  for (int m = 0; m < 79; ++m) {
    float wv = xs[PADW(base + m)];
    const int jlo = (m - 15 > 0) ? (m - 15) : 0;
    const int jhi = (m < 63) ? m : 63;
#pragma unroll
    for (int j = jlo; j <= jhi; ++j) {
      acc[m - j] = fmaf(kn[j], wv, acc[m - j]);
    }
  }
}

__global__ __launch_bounds__(256) void ista_kernel(
    const float* __restrict__ y, const float* __restrict__ pulse,
    float* __restrict__ xout) {
  __shared__ float xs0[XS_SIZE];
  __shared__ float xs1[XS_SIZE];
  __shared__ float pl[KW];
  __shared__ float kn[KW];

  const int t = threadIdx.x;
  const int row = blockIdx.x;

  if (t < KW) pl[t] = pulse[t];
  if (t < HALO) {                       // zero halos in BOTH buffers (stay zero)
    xs0[PADW(t)] = 0.0f;
    xs0[PADW(NLOG - HALO + t)] = 0.0f;
    xs1[PADW(t)] = 0.0f;
    xs1[PADW(NLOG - HALO + t)] = 0.0f;
  }
  const float* yrow = y + (size_t)row * LROW;
#pragma unroll
  for (int q = 0; q < 4; ++q) {
    int i4 = q * 256 + t;
    float4 v = ((const float4*)yrow)[i4];
    xs0[PADW(HALO + 4 * i4 + 0)] = v.x;
    xs0[PADW(HALO + 4 * i4 + 1)] = v.y;
    xs0[PADW(HALO + 4 * i4 + 2)] = v.z;
    xs0[PADW(HALO + 4 * i4 + 3)] = v.w;
  }
  __syncthreads();

  float Lc = 0.0f;
#pragma unroll
  for (int j = 0; j < KW; ++j) Lc += pl[j] * pl[j];
  const float theta = 0.1f / Lc;
  if (t < KW) kn[t] = pl[KW - 1 - t] / Lc;
  __syncthreads();

  // B_term = conv(y)/L, in registers for all iterations
  float bt[16];
  conv_row(xs0, kn, t, bt);

  // iteration 1: x1 = shrink(B_term) -> write to xs1 (xs0 no longer needed)
#pragma unroll
  for (int e = 0; e < 16; ++e)
    xs1[PADW(HALO + 16 * t + e)] = shrinkf(bt[e], theta);
  __syncthreads();

  float* cur = xs1;
  float* nxt = xs0;
  for (int it = 0; it < 19; ++it) {
    float acc[16];
    conv_row(cur, kn, t, acc);
#pragma unroll
    for (int e = 0; e < 16; ++e) {
      float xcur = cur[PADW(HALO + 16 * t + e)];
      nxt[PADW(HALO + 16 * t + e)] = shrinkf(bt[e] + xcur - acc[e], theta);
    }
    __syncthreads();                  // one barrier per iteration (double buffer)
    float* tmp = cur; cur = nxt; nxt = tmp;
  }

  float* xr = xout + (size_t)row * LROW;
#pragma unroll
  for (int q = 0; q < 4; ++q) {
    int i4 = q * 256 + t;
    float4 v;
    v.x = cur[PADW(HALO + 4 * i4 + 0)];
    v.y = cur[PADW(HALO + 4 * i4 + 1)];
    v.z = cur[PADW(HALO + 4 * i4 + 2)];
    v.w = cur[PADW(HALO + 4 * i4 + 3)];
    ((float4*)xr)[i4] = v;
  }
}

// ---------------- MLP via bf16 MFMA ----------------
// W1 pre-packed to ws: W1p[kq][c][j] = bf16(W1[8*kq + j][c]), kq=0..511, c=0..255.

__device__ __forceinline__ unsigned short f2bf(float f) {
  unsigned u = __float_as_uint(f);
  u += 0x7fffu + ((u >> 16) & 1u);     // round-to-nearest-even
  return (unsigned short)(u >> 16);
}

__global__ __launch_bounds__(256) void cast_w1(const float* __restrict__ W1,
                                               unsigned short* __restrict__ W1p) {
  const int kq = blockIdx.x;           // 512
  const int c  = threadIdx.x;          // 256
  short8 v;
#pragma unroll
  for (int j = 0; j < 8; ++j)
    v[j] = (short)f2bf(W1[(size_t)(kq * 8 + j) * 256 + c]);
  *(short8*)(W1p + ((size_t)kq * 256 + c) * 8) = v;
}

// Per block: 16 rows x all 256 cols, K=4096 in 64 tiles of BK=64.
// 256 threads = 4 waves; wave w owns cols [64w, 64w+64).
__global__ __launch_bounds__(256) void mlp_mfma(
    const float* __restrict__ x, const unsigned short* __restrict__ W1p,
    const float* __restrict__ b1, const float* __restrict__ W2,
    const float* __restrict__ b2, float* __restrict__ out1) {
  // A tile: 16 rows x 64 k as 16B blocks [row][kq], kq XOR-swizzled with row&7
  __shared__ short Ap[16 * 8 * 8];     // 2 KB
  __shared__ short Bp[8 * 256 * 8];    // 32 KB : [kq][c][j]
  __shared__ float pr[4][16];

  const int t = threadIdx.x;
  const int w = t >> 6;
  const int l = t & 63;
  const int lrow = l & 15;             // A row / B col residue
  const int lk   = l >> 4;             // k-group
  const int row0 = blockIdx.x * 16;

  f32x4 acc[4];
#pragma unroll
  for (int n = 0; n < 4; ++n) acc[n] = (f32x4)0.0f;

  for (int kt = 0; kt < 64; ++kt) {
    __syncthreads();                   // previous tile's reads complete
    // ---- stage A: x[row0..row0+16)[kt*64..+64) f32 -> bf16, swizzled
    {
      const int r  = t >> 4;           // 0..15
      const int k4 = t & 15;           // 4 consecutive k per thread
      const float4 v = *(const float4*)(x + (size_t)(row0 + r) * LROW + kt * 64 + k4 * 4);
      short4v a;
      a.x = (short)f2bf(v.x); a.y = (short)f2bf(v.y);
      a.z = (short)f2bf(v.z); a.w = (short)f2bf(v.w);
      const int kq = k4 >> 1, h = k4 & 1;
      *(short4v*)((char*)Ap + ((r * 8 + (kq ^ (r & 7))) * 16 + h * 8)) = a;
    }
    // ---- stage B: contiguous 32 KB slab copy (pre-packed layout)
    {
      const short8* src = (const short8*)(W1p + (size_t)kt * (8 * 256 * 8));
      short8* dst = (short8*)Bp;
#pragma unroll
      for (int i = 0; i < 8; ++i) dst[t + 256 * i] = src[t + 256 * i];
    }
    __syncthreads();
    // ---- MFMA: 2 k-frags x 4 n-frags
#pragma unroll
    for (int kf = 0; kf < 2; ++kf) {
      const int kq = kf * 4 + lk;
      short8 af = *(short8*)((char*)Ap + (lrow * 8 + (kq ^ (lrow & 7))) * 16);
#pragma unroll
      for (int n = 0; n < 4; ++n) {
        short8 bf = *(short8*)((char*)Bp + (kq * 256 + w * 64 + n * 16 + lrow) * 16);
        acc[n] = __builtin_amdgcn_mfma_f32_16x16x32_bf16(af, bf, acc[n], 0, 0, 0);
      }
    }
  }

  // ---- epilogue: relu(acc + b1) . W2, reduce over cols
  float s[4] = {0.0f, 0.0f, 0.0f, 0.0f};
#pragma unroll
  for (int n = 0; n < 4; ++n) {
    const int c = w * 64 + n * 16 + lrow;
    const float b1v = b1[c];
    const float w2v = W2[c];
#pragma unroll
    for (int i = 0; i < 4; ++i) {
      float f = acc[n][i] + b1v;
      f = fmaxf(f, 0.0f);
      s[i] = fmaf(f, w2v, s[i]);
    }
  }
#pragma unroll
  for (int off = 1; off < 16; off <<= 1) {
#pragma unroll
    for (int i = 0; i < 4; ++i) s[i] += __shfl_xor(s[i], off, 64);
  }
  if (lrow == 0) {
#pragma unroll
    for (int i = 0; i < 4; ++i) pr[w][lk * 4 + i] = s[i];
  }
  __syncthreads();
  if (t < 16) {
    out1[row0 + t] =
        (pr[0][t] + pr[1][t] + pr[2][t] + pr[3][t] + b2[0]) * (float)LROW;
  }
}

extern "C" void kernel_launch(void* const* d_in, const int* in_sizes, int n_in,
                              void* d_out, int out_size, void* d_ws, size_t ws_size,
                              hipStream_t stream) {
  const float* y     = (const float*)d_in[0];
  const float* pulse = (const float*)d_in[1];
  const float* W1    = (const float*)d_in[2];
  const float* b1    = (const float*)d_in[3];
  const float* W2    = (const float*)d_in[4];
  const float* b2    = (const float*)d_in[5];

  float* xout = (float*)d_out;
  float* out1 = xout + (size_t)LROW * LROW;
  unsigned short* W1p = (unsigned short*)d_ws;   // 2 MB bf16 packed W1

  cast_w1<<<512, 256, 0, stream>>>(W1, W1p);
  ista_kernel<<<LROW, 256, 0, stream>>>(y, pulse, xout);
  mlp_mfma<<<LROW / 16, 256, 0, stream>>>(xout, W1p, b1, W2, b2, out1);
}